// Round 3
// baseline (2321.544 us; speedup 1.0000x reference)
//
#include <hip/hip_runtime.h>

#define NTOT 65536      // 16*64*64 vectors
#define KC   8192       // codebook size
#define DV   64         // embedding dim
#define ZQN  4194304    // 16*64*64*64 elements of z_q

// B_k = fp32(||e_k||^2) correctly rounded (fp64 accumulate). Also zero lacc.
__global__ void vq_prep(const float* __restrict__ emb, float* __restrict__ nrm,
                        double* __restrict__ lacc) {
    int k = blockIdx.x * 256 + threadIdx.x;
    if (k == 0) *lacc = 0.0;
    double s = 0.0;
#pragma unroll
    for (int d = 0; d < DV; ++d) {
        double v = (double)emb[(size_t)k * DV + d];
        s = fma(v, v, s);
    }
    nrm[k] = (float)s;
}

// One thread per vector n. Bit-replicates numpy fp32:
//   d[n,k] = fl32( fl32(A_n + B_k) - 2*dot32(z_n, e_k) )
// with dot32 in numpy c_einsum SSE3-baseline order (4 lanes, unroll x4,
// reverse-chained mul+add, hadd tree), argmin first-index tie-break.
__global__ __launch_bounds__(256, 2) void vq_main(
    const float* __restrict__ z, const float* __restrict__ emb,
    const float* __restrict__ nrm, float* __restrict__ out,
    double* __restrict__ lacc) {
#pragma clang fp contract(off)
    __shared__ float es[64 * DV];    // 64-code fp32 tile (16 KB)
    __shared__ float Bs[64];
    __shared__ double red[4];
    const int tid = threadIdx.x;
    const int n   = blockIdx.x * 256 + tid;
    const int b   = n >> 12;         // n = (b*64 + h)*64 + w
    const int hw  = n & 4095;
    const float* zp = z + (size_t)b * 262144 + hw;   // z[b,:,h,w], stride 4096

    float zr[DV];
#pragma unroll
    for (int d = 0; d < DV; ++d)
        zr[d] = zp[(size_t)d * 4096];   // coalesced across lanes

    // A_n = fp32(||z_n||^2), correctly rounded via fp64 (one-ulp row-constant
    // differences vs numpy's pairwise order are argmin-preserving: exact
    // grid-multiple shifts commute with the final fp32 rounding).
    double ad = 0.0;
#pragma unroll
    for (int d = 0; d < DV; ++d)
        ad = fma((double)zr[d], (double)zr[d], ad);
    const float A = (float)ad;

    float dmin = 1e30f;
    int   kmin = 0;

    for (int k0 = 0; k0 < KC; k0 += 64) {
        __syncthreads();
#pragma unroll
        for (int i = 0; i < 16; ++i) {
            int j = i * 256 + tid;
            es[j] = emb[(size_t)k0 * DV + j];   // coalesced stage
        }
        if (tid < 64) Bs[tid] = nrm[k0 + tid];
        __syncthreads();

        for (int kk = 0; kk < 64; kk += 2) {
            const float* e0 = es + (kk + 0) * DV;
            const float* e1 = es + (kk + 1) * DV;
            // numpy SSE3 einsum order: lanes L=0..3, iters i=0..3,
            // vL = m[16i+L] + (m[16i+4+L] + (m[16i+8+L] + (m[16i+12+L] + vL)))
            float u0 = 0.f, u1 = 0.f, u2 = 0.f, u3 = 0.f;
            float w0 = 0.f, w1 = 0.f, w2 = 0.f, w3 = 0.f;
#pragma unroll
            for (int i = 0; i < 4; ++i) {
                const int t = 16 * i;
                u0 = (zr[t+0]*e0[t+0]) + ((zr[t+4]*e0[t+4]) + ((zr[t+8]*e0[t+8]) + ((zr[t+12]*e0[t+12]) + u0)));
                u1 = (zr[t+1]*e0[t+1]) + ((zr[t+5]*e0[t+5]) + ((zr[t+9]*e0[t+9]) + ((zr[t+13]*e0[t+13]) + u1)));
                u2 = (zr[t+2]*e0[t+2]) + ((zr[t+6]*e0[t+6]) + ((zr[t+10]*e0[t+10]) + ((zr[t+14]*e0[t+14]) + u2)));
                u3 = (zr[t+3]*e0[t+3]) + ((zr[t+7]*e0[t+7]) + ((zr[t+11]*e0[t+11]) + ((zr[t+15]*e0[t+15]) + u3)));
                w0 = (zr[t+0]*e1[t+0]) + ((zr[t+4]*e1[t+4]) + ((zr[t+8]*e1[t+8]) + ((zr[t+12]*e1[t+12]) + w0)));
                w1 = (zr[t+1]*e1[t+1]) + ((zr[t+5]*e1[t+5]) + ((zr[t+9]*e1[t+9]) + ((zr[t+13]*e1[t+13]) + w1)));
                w2 = (zr[t+2]*e1[t+2]) + ((zr[t+6]*e1[t+6]) + ((zr[t+10]*e1[t+10]) + ((zr[t+14]*e1[t+14]) + w2)));
                w3 = (zr[t+3]*e1[t+3]) + ((zr[t+7]*e1[t+7]) + ((zr[t+11]*e1[t+11]) + ((zr[t+15]*e1[t+15]) + w3)));
            }
            // _mm_hadd_ps tree: (v0+v1)+(v2+v3)
            float dot0 = (u0 + u1) + (u2 + u3);
            float dot1 = (w0 + w1) + (w2 + w3);
            // d = fl(fl(A + B) - 2*dot); 2*dot is exact in fp32
            float d0 = (A + Bs[kk + 0]) - (2.0f * dot0);
            float d1 = (A + Bs[kk + 1]) - (2.0f * dot1);
            if (d0 < dmin) { dmin = d0; kmin = k0 + kk; }
            if (d1 < dmin) { dmin = d1; kmin = k0 + kk + 1; }
        }
    }

    // index output (fp32 value in the flat fp32 out buffer)
    out[(size_t)ZQN + 1 + n] = (float)kmin;

    // z_q: out[b,c,h,w] = emb[kmin,c]
    const float* erow = emb + (size_t)kmin * DV;
    double lsum = 0.0;
#pragma unroll
    for (int c = 0; c < DV; ++c) {
        float v = erow[c];
        out[(size_t)b * 262144 + (size_t)c * 4096 + hw] = v;  // coalesced per c
        double dv = (double)v - (double)zr[c];
        lsum = fma(dv, dv, lsum);
    }

    // loss partial: wave shuffle reduce -> LDS -> one double atomic per block
#pragma unroll
    for (int off = 32; off > 0; off >>= 1)
        lsum += __shfl_down(lsum, off, 64);
    int lane = tid & 63, wv = tid >> 6;
    if (lane == 0) red[wv] = lsum;
    __syncthreads();
    if (tid == 0)
        atomicAdd(lacc, red[0] + red[1] + red[2] + red[3]);
}

__global__ void vq_fin(const double* __restrict__ lacc, float* __restrict__ out) {
    if (threadIdx.x == 0)
        out[ZQN] = (float)(1.25 * (*lacc) / (double)ZQN);
}

extern "C" void kernel_launch(void* const* d_in, const int* in_sizes, int n_in,
                              void* d_out, int out_size, void* d_ws, size_t ws_size,
                              hipStream_t stream) {
    const float* z   = (const float*)d_in[0];
    const float* emb = (const float*)d_in[1];
    float* out = (float*)d_out;
    double* lacc = (double*)d_ws;                  // 8 B
    float*  nrm  = (float*)((char*)d_ws + 64);     // 8192 fp32 = 32 KB

    vq_prep<<<KC / 256, 256, 0, stream>>>(emb, nrm, lacc);
    vq_main<<<NTOT / 256, 256, 0, stream>>>(z, emb, nrm, out, lacc);
    vq_fin<<<1, 64, 0, stream>>>(lacc, out);
}

// Round 4
// 1891.087 us; speedup vs baseline: 1.2276x; 1.2276x over previous
//
#include <hip/hip_runtime.h>

#define NTOT 65536      // 16*64*64 vectors
#define KC   8192       // codebook size
#define DV   64         // embedding dim
#define ZQN  4194304    // z_q elements
#define NSPLIT 4
#define KSLICE (KC / NSPLIT)   // 2048 codes per slice
#define TILE 64
#define MAXCAND 24
#define CSTRIDE 25      // +1 pad: breaks 8-way LDS bank conflict
#define MARGIN 6e-5f    // >= 2*(two ulp(256)/2 roundings + dot-order noise)

typedef unsigned long long u64;

// B_k = fp32(||e_k||^2) correctly rounded (fp64 accumulate); zero lacc.
__global__ void vq_prep(const float* __restrict__ emb, float* __restrict__ nrm,
                        double* __restrict__ lacc) {
    int k = blockIdx.x * 256 + threadIdx.x;
    if (k == 0) *lacc = 0.0;
    double s = 0.0;
#pragma unroll
    for (int d = 0; d < DV; ++d) {
        double v = (double)emb[(size_t)k * DV + d];
        s = fma(v, v, s);
    }
    nrm[k] = (float)s;
}

// Bit-exact numpy fp32 distance: d = fl(fl(A+B) - 2*dot), dot in c_einsum
// SSE3-baseline order (4 lanes, unroll x4, reverse-chained mul+add, hadd tree).
// VERIFIED bit-exact vs harness np reference in round 3. Keep contract OFF.
__device__ __forceinline__ float exact_d(float A, float B,
                                         const float* __restrict__ zr,
                                         const float* __restrict__ e) {
#pragma clang fp contract(off)
    float u0 = 0.f, u1 = 0.f, u2 = 0.f, u3 = 0.f;
#pragma unroll
    for (int i = 0; i < 4; ++i) {
        const int t = 16 * i;
        u0 = (zr[t+0]*e[t+0]) + ((zr[t+4]*e[t+4]) + ((zr[t+8]*e[t+8]) + ((zr[t+12]*e[t+12]) + u0)));
        u1 = (zr[t+1]*e[t+1]) + ((zr[t+5]*e[t+5]) + ((zr[t+9]*e[t+9]) + ((zr[t+13]*e[t+13]) + u1)));
        u2 = (zr[t+2]*e[t+2]) + ((zr[t+6]*e[t+6]) + ((zr[t+10]*e[t+10]) + ((zr[t+14]*e[t+14]) + u2)));
        u3 = (zr[t+3]*e[t+3]) + ((zr[t+7]*e[t+7]) + ((zr[t+11]*e[t+11]) + ((zr[t+15]*e[t+15]) + u3)));
    }
    float dot = (u0 + u1) + (u2 + u3);
    return (A + B) - (2.0f * dot);
}

// Each block: 256 vectors x one K-slice of 2048 codes. FMA screen collects
// candidate codes within MARGIN of the running screen-min (provable superset
// of the numpy argmin); exact SSE3-order rescore picks the winner. Partial
// result packed (f32bits(d)<<32)|k -> u64 min == (d, k) lexicographic min.
__global__ __launch_bounds__(256) void vq_scan(
    const float* __restrict__ z, const float* __restrict__ emb,
    const float* __restrict__ nrm, u64* __restrict__ part) {
    __shared__ float es[TILE * DV];       // 16 KB code tile
    __shared__ float Bs[TILE];
    __shared__ int   candS[256 * CSTRIDE]; // 25.6 KB candidate lists
    const int tid  = threadIdx.x;
    const int nblk = blockIdx.x & 255;
    const int s    = blockIdx.x >> 8;
    const int n    = nblk * 256 + tid;
    const int b    = n >> 12;
    const int hw   = n & 4095;
    const float* zp = z + (size_t)b * 262144 + hw;   // z[b,:,h,w], stride 4096

    float zr[DV];
#pragma unroll
    for (int d = 0; d < DV; ++d)
        zr[d] = zp[(size_t)d * 4096];                // coalesced across lanes

    int* cand = candS + tid * CSTRIDE;
    const int kbase = s * KSLICE;
    float runmin = 1e30f, thresh = 1e30f;
    int cnt = 0;

    for (int k0 = kbase; k0 < kbase + KSLICE; k0 += TILE) {
        __syncthreads();
#pragma unroll
        for (int i = 0; i < 16; ++i)
            es[i * 256 + tid] = emb[(size_t)k0 * DV + i * 256 + tid];
        if (tid < TILE) Bs[tid] = nrm[k0 + tid];
        __syncthreads();

        for (int kk = 0; kk < TILE; ++kk) {
            const float* e = es + kk * DV;
            float c0 = 0.f, c1 = 0.f, c2 = 0.f, c3 = 0.f;  // 4 FMA chains
#pragma unroll
            for (int d4 = 0; d4 < DV; d4 += 4) {
                c0 = fmaf(zr[d4+0], e[d4+0], c0);
                c1 = fmaf(zr[d4+1], e[d4+1], c1);
                c2 = fmaf(zr[d4+2], e[d4+2], c2);
                c3 = fmaf(zr[d4+3], e[d4+3], c3);
            }
            float dot = (c0 + c1) + (c2 + c3);
            float sc  = fmaf(-2.f, dot, Bs[kk]);     // screen score (A dropped)
            if (sc < thresh) {                        // rare (~10 per slice)
                if (cnt < MAXCAND) cand[cnt] = k0 + kk;
                ++cnt;
                if (sc < runmin) { runmin = sc; thresh = runmin + MARGIN; }
            }
        }
    }

    // A_n = fp32(||z_n||^2) correctly rounded (argmin-preserving vs numpy's
    // pairwise order: row-constant grid-multiple shift — verified round 3).
    double ad = 0.0;
#pragma unroll
    for (int d = 0; d < DV; ++d)
        ad = fma((double)zr[d], (double)zr[d], ad);
    const float A = (float)ad;

    float dmin = 1e30f;
    int   kmin = kbase;
    if (cnt <= MAXCAND) {
        for (int j = 0; j < cnt; ++j) {              // ascending k, strict <
            int k = cand[j];
            float d = exact_d(A, nrm[k], zr, emb + (size_t)k * DV);
            if (d < dmin) { dmin = d; kmin = k; }
        }
    } else {                                          // overflow: P ~ 1e-7
        for (int k = kbase; k < kbase + KSLICE; ++k) {
            float d = exact_d(A, nrm[k], zr, emb + (size_t)k * DV);
            if (d < dmin) { dmin = d; kmin = k; }
        }
    }
    // d > 0 always (A >= ~30), so fp32 bit pattern is order-preserving.
    part[(size_t)s * NTOT + n] = ((u64)__float_as_uint(dmin) << 32) | (unsigned)kmin;
}

// Merge NSPLIT partials (u64 min = first-index tie-break across slices),
// then fused epilogue: index write, z_q gather-store, loss partial.
__global__ __launch_bounds__(256) void vq_merge(
    const float* __restrict__ z, const float* __restrict__ emb,
    const u64* __restrict__ part, float* __restrict__ out,
    double* __restrict__ lacc) {
    __shared__ double red[4];
    const int tid = threadIdx.x;
    const int n   = blockIdx.x * 256 + tid;
    u64 best = part[n];
#pragma unroll
    for (int s = 1; s < NSPLIT; ++s) {
        u64 v = part[(size_t)s * NTOT + n];
        if (v < best) best = v;
    }
    const int kmin = (int)(best & 0xffffffffu);
    out[(size_t)ZQN + 1 + n] = (float)kmin;

    const int b  = n >> 12;
    const int hw = n & 4095;
    const float* zp   = z + (size_t)b * 262144 + hw;
    const float* erow = emb + (size_t)kmin * DV;
    double lsum = 0.0;
#pragma unroll
    for (int c = 0; c < DV; ++c) {
        float v = erow[c];
        out[(size_t)b * 262144 + (size_t)c * 4096 + hw] = v;  // coalesced per c
        double dv = (double)v - (double)zp[(size_t)c * 4096];
        lsum = fma(dv, dv, lsum);
    }
#pragma unroll
    for (int off = 32; off > 0; off >>= 1)
        lsum += __shfl_down(lsum, off, 64);
    if ((tid & 63) == 0) red[tid >> 6] = lsum;
    __syncthreads();
    if (tid == 0)
        atomicAdd(lacc, red[0] + red[1] + red[2] + red[3]);
}

__global__ void vq_fin(const double* __restrict__ lacc, float* __restrict__ out) {
    if (threadIdx.x == 0)
        out[ZQN] = (float)(1.25 * (*lacc) / (double)ZQN);
}

extern "C" void kernel_launch(void* const* d_in, const int* in_sizes, int n_in,
                              void* d_out, int out_size, void* d_ws, size_t ws_size,
                              hipStream_t stream) {
    const float* z   = (const float*)d_in[0];
    const float* emb = (const float*)d_in[1];
    float* out = (float*)d_out;
    double* lacc = (double*)d_ws;                       // 8 B
    float*  nrm  = (float*)((char*)d_ws + 64);          // 32 KB
    u64*    part = (u64*)((char*)d_ws + 64 + 32768);    // 4*65536*8 = 2 MB

    vq_prep<<<KC / 256, 256, 0, stream>>>(emb, nrm, lacc);
    vq_scan<<<NSPLIT * 256, 256, 0, stream>>>(z, emb, nrm, part);
    vq_merge<<<NTOT / 256, 256, 0, stream>>>(z, emb, part, out, lacc);
    vq_fin<<<1, 64, 0, stream>>>(lacc, out);
}

// Round 5
// 269.630 us; speedup vs baseline: 8.6101x; 7.0136x over previous
//
#include <hip/hip_runtime.h>

#define NTOT 65536      // 16*64*64 vectors
#define KC   8192       // codebook size
#define DV   64         // embedding dim
#define ZQN  4194304    // z_q elements
#define MAXC 16         // candidate slots per n
#define TH   3e-5f      // dot-space margin: covers numpy rounding (1.2e-5) +
                        // bf16 screen noise (17 sigma) + ||e||^2 (1e-6)

typedef unsigned int u32;
typedef short short8 __attribute__((ext_vector_type(8)));   // 8 bf16
typedef float float4v __attribute__((ext_vector_type(4)));  // MFMA acc

__device__ __forceinline__ short f2bf(float x) {           // fp32->bf16 RNE
    u32 u = __float_as_uint(x);
    u32 r = (u + 0x7fffu + ((u >> 16) & 1u)) >> 16;
    return (short)r;
}
// monotone fp32 <-> u32 key for atomicMax
__device__ __forceinline__ u32 fenc(float x) {
    u32 b = __float_as_uint(x);
    return (b & 0x80000000u) ? ~b : (b | 0x80000000u);
}
__device__ __forceinline__ float fdec(u32 k) {
    u32 b = (k & 0x80000000u) ? (k & 0x7fffffffu) : ~k;
    return __uint_as_float(b);
}

// Bit-exact numpy fp32 distance (VERIFIED bit-exact in rounds 3/4):
// d = fl(fl(A+B) - 2*dot), dot in c_einsum SSE3-baseline order.
__device__ __forceinline__ float exact_d(float A, float B,
                                         const float* __restrict__ zr,
                                         const float* __restrict__ e) {
#pragma clang fp contract(off)
    float u0 = 0.f, u1 = 0.f, u2 = 0.f, u3 = 0.f;
#pragma unroll
    for (int i = 0; i < 4; ++i) {
        const int t = 16 * i;
        u0 = (zr[t+0]*e[t+0]) + ((zr[t+4]*e[t+4]) + ((zr[t+8]*e[t+8]) + ((zr[t+12]*e[t+12]) + u0)));
        u1 = (zr[t+1]*e[t+1]) + ((zr[t+5]*e[t+5]) + ((zr[t+9]*e[t+9]) + ((zr[t+13]*e[t+13]) + u1)));
        u2 = (zr[t+2]*e[t+2]) + ((zr[t+6]*e[t+6]) + ((zr[t+10]*e[t+10]) + ((zr[t+14]*e[t+14]) + u2)));
        u3 = (zr[t+3]*e[t+3]) + ((zr[t+7]*e[t+7]) + ((zr[t+11]*e[t+11]) + ((zr[t+15]*e[t+15]) + u3)));
    }
    float dot = (u0 + u1) + (u2 + u3);
    return (A + B) - (2.0f * dot);
}

// prep: pack emb -> bf16 codebook (eb), ||e_k||^2 (fp64->fp32), zero counters.
__global__ __launch_bounds__(256) void vq_prep(
    const float* __restrict__ emb, float* __restrict__ nrm,
    u32* __restrict__ cnt, u32* __restrict__ dmkey,
    double* __restrict__ lacc, ushort2* __restrict__ ebp) {
    int tid = blockIdx.x * 256 + threadIdx.x;        // 262144 threads
    float a = emb[2 * tid], b = emb[2 * tid + 1];    // 524288 = KC*DV elems
    ushort2 p;
    p.x = (unsigned short)f2bf(a);
    p.y = (unsigned short)f2bf(b);
    ebp[tid] = p;
    if (tid < KC) {
        double s = 0.0;
#pragma unroll
        for (int d = 0; d < DV; ++d) {
            double v = (double)emb[(size_t)tid * DV + d];
            s = fma(v, v, s);
        }
        nrm[tid] = (float)s;
    }
    if (tid < NTOT) { cnt[tid] = 0u; dmkey[tid] = 0u; }
    if (tid == 0) *lacc = 0.0;
}

// MFMA screen. MODE 0: per-n max bf16-dot (atomicMax). MODE 1: collect all k
// with dot >= dotmax - TH (bitwise-identical MFMA -> superset incl. the max).
// Wave: 16 codes x 64 n (4 n-subtiles share A-frags). Grid: 256 n-blocks x
// 4 k-slices. mfma_f32_16x16x32_bf16: A[m=lane&15][k=quad*8+j],
// B[k=quad*8+j][n=lane&15], C: col=lane&15, row=quad*4+reg (m89/m91/m92).
template <int MODE>
__global__ __launch_bounds__(256, 4) void vq_pass(
    const float* __restrict__ z, const unsigned short* __restrict__ eb,
    u32* __restrict__ dmkey, u32* __restrict__ cnt, int* __restrict__ cand) {
    __shared__ int4 tile[256];                       // 32 codes x 64 d, frag order
    const int tid = threadIdx.x;
    const int lane = tid & 63, wv = tid >> 6;
    const int nblk = blockIdx.x & 255, ks = blockIdx.x >> 8;
    const int nb = nblk * 256 + wv * 64;             // wave's 64 n
    const int col = lane & 15, quad = lane >> 4;
    const int nlo = nb + col;

    // z B-fragments (bf16 RNE), kept in VGPRs for the whole k-loop
    short8 zf[4][2];
#pragma unroll
    for (int ns = 0; ns < 4; ++ns) {
        int n = nlo + ns * 16;
        const float* zp = z + (size_t)(n >> 12) * 262144 + (n & 4095);
#pragma unroll
        for (int t = 0; t < 2; ++t)
#pragma unroll
            for (int j = 0; j < 8; ++j)
                zf[ns][t][j] = f2bf(zp[(size_t)(t * 32 + quad * 8 + j) * 4096]);
    }

    float rmax[4] = {-1e30f, -1e30f, -1e30f, -1e30f};
    float thr[4];
    if (MODE == 1) {
#pragma unroll
        for (int ns = 0; ns < 4; ++ns)
            thr[ns] = fdec(dmkey[nlo + ns * 16]) - TH;
    }

    // this thread's staging chunk: tid = sub*128 + t*64 + sl
    const int sl = tid & 63;
    const size_t soff = (size_t)((tid >> 7) * 16 + (sl & 15)) * 64 +
                        ((tid >> 6) & 1) * 32 + (sl >> 4) * 8;
    const int kbase = ks * 2048;

    for (int k0 = kbase; k0 < kbase + 2048; k0 += 32) {
        __syncthreads();
        tile[tid] = *reinterpret_cast<const int4*>(eb + (size_t)k0 * 64 + soff);
        __syncthreads();
#pragma unroll
        for (int sub = 0; sub < 2; ++sub) {
            short8 a0 = *reinterpret_cast<const short8*>(&tile[(sub * 2 + 0) * 64 + lane]);
            short8 a1 = *reinterpret_cast<const short8*>(&tile[(sub * 2 + 1) * 64 + lane]);
#pragma unroll
            for (int ns = 0; ns < 4; ++ns) {
                float4v acc = {0.f, 0.f, 0.f, 0.f};
                acc = __builtin_amdgcn_mfma_f32_16x16x32_bf16(a0, zf[ns][0], acc, 0, 0, 0);
                acc = __builtin_amdgcn_mfma_f32_16x16x32_bf16(a1, zf[ns][1], acc, 0, 0, 0);
                if (MODE == 0) {
                    rmax[ns] = fmaxf(rmax[ns],
                               fmaxf(fmaxf(acc[0], acc[1]), fmaxf(acc[2], acc[3])));
                } else {
#pragma unroll
                    for (int r = 0; r < 4; ++r) {
                        if (acc[r] >= thr[ns]) {                   // rare
                            int n = nlo + ns * 16;
                            u32 pos = atomicAdd(&cnt[n], 1u);
                            if (pos < MAXC)
                                cand[(size_t)n * MAXC + pos] = k0 + sub * 16 + quad * 4 + r;
                        }
                    }
                }
            }
        }
    }
    if (MODE == 0) {
#pragma unroll
        for (int ns = 0; ns < 4; ++ns) {
            float m = rmax[ns];
            m = fmaxf(m, __shfl_xor(m, 16));
            m = fmaxf(m, __shfl_xor(m, 32));
            if (quad == 0) atomicMax(&dmkey[nlo + ns * 16], fenc(m));
        }
    }
}

// E1: exact (numpy-bit-identical) rescore of the candidates -> index.
__global__ __launch_bounds__(256) void vq_e1(
    const float* __restrict__ z, const float* __restrict__ emb,
    const float* __restrict__ nrm, const u32* __restrict__ cnt,
    const int* __restrict__ cand, int* __restrict__ idxw,
    float* __restrict__ out) {
    const int n = blockIdx.x * 256 + threadIdx.x;
    const float* zp = z + (size_t)(n >> 12) * 262144 + (n & 4095);
    float zr[DV];
#pragma unroll
    for (int d = 0; d < DV; ++d) zr[d] = zp[(size_t)d * 4096];
    double ad = 0.0;
#pragma unroll
    for (int d = 0; d < DV; ++d) ad = fma((double)zr[d], (double)zr[d], ad);
    const float A = (float)ad;

    float dmin = 1e30f;
    int kmin = 0;
    u32 c = cnt[n];
    if (c <= MAXC) {
        for (u32 j = 0; j < c; ++j) {                 // unordered -> lex min
            int k = cand[(size_t)n * MAXC + j];
            float d = exact_d(A, nrm[k], zr, emb + (size_t)k * DV);
            if (d < dmin || (d == dmin && k < kmin)) { dmin = d; kmin = k; }
        }
    } else {                                          // overflow: ~never
        for (int k = 0; k < KC; ++k) {
            float d = exact_d(A, nrm[k], zr, emb + (size_t)k * DV);
            if (d < dmin) { dmin = d; kmin = k; }
        }
    }
    idxw[n] = kmin;
    out[(size_t)ZQN + 1 + n] = (float)kmin;
}

// E2: z_q gather-store + loss (runs after E1; overwrites the out-scratch).
__global__ __launch_bounds__(256) void vq_e2(
    const float* __restrict__ z, const float* __restrict__ emb,
    const int* __restrict__ idxw, float* __restrict__ out,
    double* __restrict__ lacc) {
    __shared__ double red[4];
    const int tid = threadIdx.x;
    const int n = blockIdx.x * 256 + tid;
    const int b = n >> 12, hw = n & 4095;
    const int kmin = idxw[n];
    const float* zp = z + (size_t)b * 262144 + hw;
    const float* erow = emb + (size_t)kmin * DV;
    double lsum = 0.0;
#pragma unroll
    for (int c = 0; c < DV; ++c) {
        float v = erow[c];
        out[(size_t)b * 262144 + (size_t)c * 4096 + hw] = v;   // coalesced per c
        double dv = (double)v - (double)zp[(size_t)c * 4096];
        lsum = fma(dv, dv, lsum);
    }
#pragma unroll
    for (int off = 32; off > 0; off >>= 1)
        lsum += __shfl_down(lsum, off, 64);
    if ((tid & 63) == 0) red[tid >> 6] = lsum;
    __syncthreads();
    if (tid == 0)
        atomicAdd(lacc, red[0] + red[1] + red[2] + red[3]);
}

__global__ void vq_fin(const double* __restrict__ lacc, float* __restrict__ out) {
    if (threadIdx.x == 0)
        out[ZQN] = (float)(1.25 * (*lacc) / (double)ZQN);
}

extern "C" void kernel_launch(void* const* d_in, const int* in_sizes, int n_in,
                              void* d_out, int out_size, void* d_ws, size_t ws_size,
                              hipStream_t stream) {
    const float* z   = (const float*)d_in[0];
    const float* emb = (const float*)d_in[1];
    float* out = (float*)d_out;

    // out-region scratch (z_q span is 16.8 MB, rewritten by E2 at the end):
    int*            cand = (int*)d_out;                               // 4 MB
    unsigned short* eb   = (unsigned short*)((char*)d_out + 4194304); // 1 MB
    // ws scratch (<= 820 KB, well under the proven 2.1 MB):
    double* lacc  = (double*)d_ws;
    float*  nrm   = (float*)((char*)d_ws + 64);          // 32 KB
    u32*    dmkey = (u32*)((char*)d_ws + 32832);         // 256 KB
    u32*    cnt   = (u32*)((char*)d_ws + 294976);        // 256 KB
    int*    idxw  = (int*)((char*)d_ws + 557120);        // 256 KB

    vq_prep<<<1024, 256, 0, stream>>>(emb, nrm, cnt, dmkey, lacc, (ushort2*)eb);
    vq_pass<0><<<1024, 256, 0, stream>>>(z, eb, dmkey, cnt, cand);
    vq_pass<1><<<1024, 256, 0, stream>>>(z, eb, dmkey, cnt, cand);
    vq_e1<<<256, 256, 0, stream>>>(z, emb, nrm, cnt, cand, idxw, out);
    vq_e2<<<256, 256, 0, stream>>>(z, emb, idxw, out, lacc);
    vq_fin<<<1, 64, 0, stream>>>(lacc, out);
}